// Round 1
// baseline (193.125 us; speedup 1.0000x reference)
//
#include <hip/hip_runtime.h>
#include <math.h>
#include <float.h>

// Problem constants (B=8, T=64 -> 512 frames)
#define NF 512
#define NQ 900
#define NG 24

#define C_CLS 1.0f
#define C_L1  5.0f
#define C_GIOU 2.0f
#define ALPHA 0.25f

// GIoU for two cxcywh boxes, f32, mirroring the JAX reference exactly.
__device__ __forceinline__ float giou_f(const float4 a, const float4 b) {
    float ax1 = a.x - 0.5f * a.z, ay1 = a.y - 0.5f * a.w;
    float ax2 = a.x + 0.5f * a.z, ay2 = a.y + 0.5f * a.w;
    float bx1 = b.x - 0.5f * b.z, by1 = b.y - 0.5f * b.w;
    float bx2 = b.x + 0.5f * b.z, by2 = b.y + 0.5f * b.w;
    float ix1 = fmaxf(ax1, bx1), iy1 = fmaxf(ay1, by1);
    float ix2 = fminf(ax2, bx2), iy2 = fminf(ay2, by2);
    float inter = fmaxf(ix2 - ix1, 0.0f) * fmaxf(iy2 - iy1, 0.0f);
    float aa = (ax2 - ax1) * (ay2 - ay1);
    float ab = (bx2 - bx1) * (by2 - by1);
    float un = aa + ab - inter;
    float iou = inter / fmaxf(un, 1e-6f);
    float ex1 = fminf(ax1, bx1), ey1 = fminf(ay1, by1);
    float ex2 = fmaxf(ax2, bx2), ey2 = fmaxf(ay2, by2);
    float enc = (ex2 - ex1) * (ey2 - ey1);
    return iou - (enc - un) / fmaxf(enc, 1e-6f);
}

__device__ __forceinline__ float softplusf_(float x) {
    // stable log(1+exp(x))
    return fmaxf(x, 0.0f) + log1pf(expf(-fabsf(x)));
}

// ---------------------------------------------------------------------------
// Kernel 1: build transposed cost matrices  cost[f][g][q]  (NG x NQ per frame)
// ---------------------------------------------------------------------------
__global__ __launch_bounds__(256) void cost_kernel(
        const float* __restrict__ bboxes,   // (NF, NQ, 4) cxcywh
        const float* __restrict__ scores,   // (NF, NQ, 1)
        const float* __restrict__ gt,       // (NF, NG, 4)
        float* __restrict__ cost)           // (NF, NG, NQ)
{
    const int f = blockIdx.x;
    const int tid = threadIdx.x;
    __shared__ float4 sgt[NG];
    if (tid < NG) sgt[tid] = reinterpret_cast<const float4*>(gt + (size_t)f * NG * 4)[tid];
    __syncthreads();

    const float4* bb = reinterpret_cast<const float4*>(bboxes + (size_t)f * NQ * 4);
    const float* sc = scores + (size_t)f * NQ;
    float* Cf = cost + (size_t)f * NG * NQ;

    for (int q = tid; q < NQ; q += 256) {
        float4 a = bb[q];
        float x = sc[q];
        float prob = 1.0f / (1.0f + expf(-x));
        float ccls = -prob;
        #pragma unroll
        for (int g = 0; g < NG; ++g) {
            float4 b = sgt[g];
            float l1 = fabsf(a.x - b.x) + fabsf(a.y - b.y) + fabsf(a.z - b.z) + fabsf(a.w - b.w);
            float gi = giou_f(a, b);
            Cf[(size_t)g * NQ + q] = C_CLS * ccls + C_L1 * l1 - C_GIOU * gi;
        }
    }
}

// ---------------------------------------------------------------------------
// Kernel 2: exact rectangular Hungarian (Jonker-Volgenant w/ potentials),
// one block per frame, n=NG rows, m=NQ cols. Mirrors the numpy reference:
// doubles for u/v/minv, first-occurrence (smallest j) tie-break in argmin.
// Column ownership: thread tid owns j in {tid, tid+256, ...} (j in 0..NQ).
// ---------------------------------------------------------------------------
__global__ __launch_bounds__(256) void hungarian_kernel(
        const float* __restrict__ cost,     // (NF, NG, NQ)
        int* __restrict__ match)            // (NF, NG) -> query index per GT
{
    const int f = blockIdx.x;
    const int tid = threadIdx.x;
    const float* C = cost + (size_t)f * NG * NQ;

    __shared__ double u_[NG + 1];
    __shared__ double v_[NQ + 1];
    __shared__ double minv[NQ + 1];
    __shared__ int p[NQ + 1];
    __shared__ int way[NQ + 1];
    __shared__ unsigned char used[NQ + 1];
    __shared__ double rv[256];
    __shared__ int ri[256];

    for (int j = tid; j <= NQ; j += 256) { v_[j] = 0.0; p[j] = 0; }
    if (tid <= NG) u_[tid] = 0.0;
    __syncthreads();

    for (int i = 1; i <= NG; ++i) {
        for (int j = tid; j <= NQ; j += 256) { minv[j] = DBL_MAX; used[j] = 0; }
        if (tid == 0) p[0] = i;
        __syncthreads();

        int j0 = 0;
        while (true) {
            // owner of column j0 marks it used (only the owner ever reads it)
            if ((j0 & 255) == tid) used[j0] = 1;
            const int i0 = p[j0];
            const double ui0 = u_[i0];
            const float* Crow = C + (size_t)(i0 - 1) * NQ;

            // scan owned unused columns: relax minv, track local argmin
            double best = DBL_MAX;
            int bestj = NQ + 1;
            for (int j = tid; j <= NQ; j += 256) {
                if (j >= 1 && !used[j]) {
                    double cur = (double)Crow[j - 1] - ui0 - v_[j];
                    if (cur < minv[j]) { minv[j] = cur; way[j] = j0; }
                    double mv = minv[j];
                    if (mv < best || (mv == best && j < bestj)) { best = mv; bestj = j; }
                }
            }
            rv[tid] = best; ri[tid] = bestj;
            __syncthreads();
            // block argmin, ties -> smallest j (matches np.argmin first occurrence)
            for (int s = 128; s > 0; s >>= 1) {
                if (tid < s) {
                    double ov = rv[tid + s]; int oi = ri[tid + s];
                    if (ov < rv[tid] || (ov == rv[tid] && oi < ri[tid])) { rv[tid] = ov; ri[tid] = oi; }
                }
                __syncthreads();
            }
            const double delta = rv[0];
            const int j1 = ri[0];

            // potential update on owned columns (u indices are distinct rows)
            for (int j = tid; j <= NQ; j += 256) {
                if (used[j]) { u_[p[j]] += delta; v_[j] -= delta; }
                else          { minv[j] -= delta; }
            }
            __syncthreads();

            j0 = j1;
            if (p[j0] == 0) break;   // p unchanged inside loop: consistent across threads
        }

        // augment along the alternating path (serial, tiny)
        if (tid == 0) {
            int jj = j0;
            while (jj) { int jn = way[jj]; p[jj] = p[jn]; jj = jn; }
        }
        __syncthreads();
    }

    for (int j = tid; j <= NQ; j += 256) {
        if (j >= 1 && p[j] > 0) match[(size_t)f * NG + (p[j] - 1)] = j - 1;
    }
}

// ---------------------------------------------------------------------------
// Kernel 3: loss. One block per frame; atomicAdd per-frame total / 512.
// ---------------------------------------------------------------------------
__global__ void zero_kernel(float* __restrict__ out) { out[0] = 0.0f; }

__global__ __launch_bounds__(256) void loss_kernel(
        const float* __restrict__ bboxes,
        const float* __restrict__ scores,
        const float* __restrict__ gt,
        const int* __restrict__ match,
        float* __restrict__ out)
{
    const int f = blockIdx.x;
    const int tid = threadIdx.x;
    __shared__ unsigned char tgt[NQ];
    __shared__ float rsum[256];

    for (int q = tid; q < NQ; q += 256) tgt[q] = 0;
    __syncthreads();
    if (tid < NG) tgt[match[(size_t)f * NG + tid]] = 1;
    __syncthreads();

    // focal classification loss over all queries
    const float* sc = scores + (size_t)f * NQ;
    float sum_cls = 0.0f;
    for (int q = tid; q < NQ; q += 256) {
        float x = sc[q];
        float t = tgt[q] ? 1.0f : 0.0f;
        float ce = t * softplusf_(-x) + (1.0f - t) * softplusf_(x);
        float prob = 1.0f / (1.0f + expf(-x));
        float pt = prob * t + (1.0f - prob) * (1.0f - t);
        float om = 1.0f - pt;
        float fw = (ALPHA * t + (1.0f - ALPHA) * (1.0f - t)) * om * om;
        sum_cls += fw * ce;
    }

    // matched-box L1 + GIoU (one GT per thread for tid < NG)
    float sum_l1 = 0.0f, sum_g = 0.0f;
    if (tid < NG) {
        int q = match[(size_t)f * NG + tid];
        float4 a = reinterpret_cast<const float4*>(bboxes + (size_t)f * NQ * 4)[q];
        float4 b = reinterpret_cast<const float4*>(gt + (size_t)f * NG * 4)[tid];
        sum_l1 = fabsf(a.x - b.x) + fabsf(a.y - b.y) + fabsf(a.z - b.z) + fabsf(a.w - b.w);
        sum_g = 1.0f - giou_f(a, b);
    }

    // frame total = mean_cls + 5*mean_l1(over NG*4) + 2*mean_giou(over NG)
    float val = sum_cls * (1.0f / (float)NQ)
              + sum_l1 * (C_L1 / (float)(NG * 4))
              + sum_g  * (C_GIOU / (float)NG);
    rsum[tid] = val;
    __syncthreads();
    for (int s = 128; s > 0; s >>= 1) {
        if (tid < s) rsum[tid] += rsum[tid + s];
        __syncthreads();
    }
    if (tid == 0) atomicAdd(out, rsum[0] * (1.0f / (float)NF));
}

extern "C" void kernel_launch(void* const* d_in, const int* in_sizes, int n_in,
                              void* d_out, int out_size, void* d_ws, size_t ws_size,
                              hipStream_t stream) {
    const float* bboxes = (const float*)d_in[0];
    const float* scores = (const float*)d_in[1];
    const float* gt     = (const float*)d_in[2];
    float* out = (float*)d_out;

    float* cost = (float*)d_ws;
    int* match = (int*)((char*)d_ws + (size_t)NF * NG * NQ * sizeof(float));

    hipLaunchKernelGGL(cost_kernel, dim3(NF), dim3(256), 0, stream, bboxes, scores, gt, cost);
    hipLaunchKernelGGL(hungarian_kernel, dim3(NF), dim3(256), 0, stream, cost, match);
    hipLaunchKernelGGL(zero_kernel, dim3(1), dim3(1), 0, stream, out);
    hipLaunchKernelGGL(loss_kernel, dim3(NF), dim3(256), 0, stream, bboxes, scores, gt, match, out);
}